// Round 7
// baseline (182.715 us; speedup 1.0000x reference)
//
#include <hip/hip_runtime.h>
#include <hip/hip_bf16.h>

#define NROWS 8192
#define KD    1024

typedef __attribute__((ext_vector_type(8))) short bf16x8;
typedef __attribute__((ext_vector_type(4))) float f32x4;

__device__ unsigned short g_x1n[(size_t)NROWS * KD];
__device__ unsigned short g_x2n[(size_t)NROWS * KD];

__device__ __forceinline__ unsigned short f2bf(float f) {
    union { float f; unsigned u; } x; x.f = f;
    return (unsigned short)((x.u + 0x7fffu + ((x.u >> 16) & 1u)) >> 16);  // RNE
}

__global__ __launch_bounds__(256) void norm_cast_kernel(const float* __restrict__ x1,
                                                        const float* __restrict__ x2) {
    int row = blockIdx.x;
    const float* src;
    unsigned short* dst;
    if (row < NROWS) { src = x1 + (size_t)row * KD;           dst = g_x1n + (size_t)row * KD; }
    else             { src = x2 + (size_t)(row - NROWS) * KD; dst = g_x2n + (size_t)(row - NROWS) * KD; }

    int t = threadIdx.x;
    float4 v = ((const float4*)src)[t];
    float s = v.x * v.x + v.y * v.y + v.z * v.z + v.w * v.w;
    #pragma unroll
    for (int off = 32; off > 0; off >>= 1) s += __shfl_down(s, off);

    __shared__ float red[4];
    if ((t & 63) == 0) red[t >> 6] = s;
    __syncthreads();
    float tot = red[0] + red[1] + red[2] + red[3];
    float inv = 1.0f / fmaxf(sqrtf(tot), 1e-8f);

    ushort4 o;
    o.x = f2bf(v.x * inv); o.y = f2bf(v.y * inv);
    o.z = f2bf(v.z * inv); o.w = f2bf(v.w * inv);
    ((ushort4*)dst)[t] = o;
}

__device__ __forceinline__ void gload_lds16(const unsigned short* g, unsigned short* l) {
    __builtin_amdgcn_global_load_lds((const __attribute__((address_space(1))) void*)g,
                                     (__attribute__((address_space(3))) void*)l,
                                     16, 0, 0);
}

#define BARX() do { asm volatile("" ::: "memory"); __builtin_amdgcn_s_barrier(); \
                    asm volatile("" ::: "memory"); } while (0)
#define MFMA16(a, b, c) __builtin_amdgcn_mfma_f32_16x16x32_bf16((a), (b), (c), 0, 0, 0)

struct Ctx {
    const unsigned short* srcA;   // advancing: next tile's k-col (incl. trow*KD + scol)
    const unsigned short* srcB;
    unsigned short* ldsf;
    int ldst;                     // t*8
    int aoff0, aoff1, boff0, boff1;
    int wr, wch;
};

__device__ __forceinline__ void stage_half2(Ctx& c, bool isA, int hbit, int region) {
    const unsigned short* src = (isA ? c.srcA : c.srcB) + (size_t)hbit * 128 * KD;
    unsigned short* dst = c.ldsf + region * 8192 + c.ldst;
    gload_lds16(src, dst);
    gload_lds16(src + (size_t)64 * KD, dst + 4096);
}

// One K-tile: B-resident (Bc, read last tile), A streamed 2 rows ahead.
// Single barrier per tile: [stage T+1 | A-stream + 56 MFMA | vmcnt0+lgkm0+bar |
// read Bn(T+1) | 8 MFMA (mi=7)]. Race ledger in analysis.
template<int BUF, int MODE>   // MODE 0 steady; 1 = last tile (no stage/barrier/Bn)
__device__ __forceinline__ void tile_body(Ctx& c, f32x4 (&acc)[8][4],
                                          bf16x8 (&Bc)[4][2], bf16x8 (&Bn)[4][2]) {
    if (MODE == 0) {
        stage_half2(c, true,  0, (BUF ^ 1) * 4 + 0);
        stage_half2(c, true,  1, (BUF ^ 1) * 4 + 1);
        stage_half2(c, false, 0, (BUF ^ 1) * 4 + 2);
        stage_half2(c, false, 1, (BUF ^ 1) * 4 + 3);
        c.srcA += 64; c.srcB += 64;
    }
    __builtin_amdgcn_sched_barrier(0);   // pin stage issue at tile top

    const unsigned short* ab  = c.ldsf + (BUF * 4 + c.wr) * 8192;
    const unsigned short* bbn = c.ldsf + ((BUF ^ 1) * 4 + 2 + c.wch) * 8192;

    bf16x8 A[4][2];
    A[0][0] = *(const bf16x8*)(ab + 0 * 1024 + c.aoff0);
    A[0][1] = *(const bf16x8*)(ab + 0 * 1024 + c.aoff1);
    A[1][0] = *(const bf16x8*)(ab + 1 * 1024 + c.aoff0);
    A[1][1] = *(const bf16x8*)(ab + 1 * 1024 + c.aoff1);

    #pragma unroll
    for (int mi = 0; mi < 7; ++mi) {
        if (mi < 6) {
            A[(mi + 2) & 3][0] = *(const bf16x8*)(ab + (mi + 2) * 1024 + c.aoff0);
            A[(mi + 2) & 3][1] = *(const bf16x8*)(ab + (mi + 2) * 1024 + c.aoff1);
        }
        #pragma unroll
        for (int ni = 0; ni < 4; ++ni) {
            acc[mi][ni] = MFMA16(A[mi & 3][0], Bc[ni][0], acc[mi][ni]);
            acc[mi][ni] = MFMA16(A[mi & 3][1], Bc[ni][1], acc[mi][ni]);
        }
    }

    if (MODE == 0) {
        // Publish point: my stages landed (vmcnt0), my LDS reads retired (lgkm0).
        asm volatile("s_waitcnt vmcnt(0) lgkmcnt(0)" ::: "memory");
        BARX();
        // Cross-boundary read-ahead: next tile's B (staged this tile, just published).
        #pragma unroll
        for (int ni = 0; ni < 4; ++ni) {
            Bn[ni][0] = *(const bf16x8*)(bbn + ni * 1024 + c.boff0);
            Bn[ni][1] = *(const bf16x8*)(bbn + ni * 1024 + c.boff1);
        }
    }

    // mi = 7 (hides Bn-read latency under MFMA)
    __builtin_amdgcn_s_setprio(1);
    #pragma unroll
    for (int ni = 0; ni < 4; ++ni) {
        acc[7][ni] = MFMA16(A[3][0], Bc[ni][0], acc[7][ni]);
        acc[7][ni] = MFMA16(A[3][1], Bc[ni][1], acc[7][ni]);
    }
    __builtin_amdgcn_s_setprio(0);
}

// 256x256 tile, BK=64, 8 waves (2M x 4N), B-resident/A-streamed schedule.
__global__ __launch_bounds__(512, 2) void gemm8_kernel(float* __restrict__ C) {
    __shared__ unsigned short lds[2][4][8192];   // 128 KiB

    // L2-rectangle XCD mapping (bijective), bn-band pinned per XCD (round 5: FETCH -63%).
    int bid = blockIdx.x;                 // 1024 blocks
    int xcd  = bid & 7;
    int idx  = bid >> 3;
    int rnd  = idx >> 5;
    int j    = idx & 31;
    int rect = rnd * 8 + xcd;
    int bm = (rect >> 2) * 4 + (j >> 3);
    int bn = (rect & 3) * 8 + (j & 7);

    int t = threadIdx.x;
    int lane = t & 63, wid = t >> 6;
    int wr = wid >> 2, wc = wid & 3;
    int r = lane & 15;
    int s0 = (lane >> 4) ^ (r & 7);       // swizzled 16B slot, kk=0
    int s1 = s0 ^ 4;                      // kk=1

    Ctx c;
    {
        int trow = t >> 3;
        int scol = ((t & 7) ^ (trow & 7)) * 8;   // inverse swizzle on global source
        c.srcA = g_x1n + (size_t)bm * 256 * KD + (size_t)trow * KD + scol;
        c.srcB = g_x2n + (size_t)bn * 256 * KD + (size_t)trow * KD + scol;
    }
    c.ldsf = &lds[0][0][0];
    c.ldst = t * 8;
    c.aoff0 = r * 64 + s0 * 8;
    c.aoff1 = r * 64 + s1 * 8;
    c.boff0 = ((wc & 1) * 64 + r) * 64 + s0 * 8;
    c.boff1 = ((wc & 1) * 64 + r) * 64 + s1 * 8;
    c.wr = wr;
    c.wch = wc >> 1;

    f32x4 acc[8][4] = {};
    bf16x8 B0r[4][2], B1r[4][2];

    // Prologue: stage tile 0 into buf0; drain; publish; preload Bcur(tile0).
    stage_half2(c, true,  0, 0);
    stage_half2(c, true,  1, 1);
    stage_half2(c, false, 0, 2);
    stage_half2(c, false, 1, 3);
    c.srcA += 64; c.srcB += 64;
    asm volatile("s_waitcnt vmcnt(0)" ::: "memory");
    BARX();
    {
        const unsigned short* bb0 = c.ldsf + (2 + c.wch) * 8192;
        #pragma unroll
        for (int ni = 0; ni < 4; ++ni) {
            B0r[ni][0] = *(const bf16x8*)(bb0 + ni * 1024 + c.boff0);
            B0r[ni][1] = *(const bf16x8*)(bb0 + ni * 1024 + c.boff1);
        }
    }

    for (int it = 0; it < 7; ++it) {      // tiles 0..13 (stage 1..14)
        tile_body<0, 0>(c, acc, B0r, B1r);
        tile_body<1, 0>(c, acc, B1r, B0r);
    }
    tile_body<0, 0>(c, acc, B0r, B1r);    // tile 14, stages+reads B(15)
    tile_body<1, 1>(c, acc, B1r, B0r);    // tile 15

    // Epilogue: C/D layout col = lane&15, row = (lane>>4)*4 + j.
    int cn = lane & 15, rq = (lane >> 4) * 4;
    int rbase = bm * 256 + wr * 128;
    int cbase = bn * 256 + wc * 64;
    #pragma unroll
    for (int mi = 0; mi < 8; ++mi)
        #pragma unroll
        for (int ni = 0; ni < 4; ++ni)
            #pragma unroll
            for (int j2 = 0; j2 < 4; ++j2)
                C[(size_t)(rbase + mi * 16 + rq + j2) * NROWS + cbase + ni * 16 + cn] =
                    acc[mi][ni][j2] * 20.0f;
}

extern "C" void kernel_launch(void* const* d_in, const int* in_sizes, int n_in,
                              void* d_out, int out_size, void* d_ws, size_t ws_size,
                              hipStream_t stream) {
    (void)in_sizes; (void)n_in; (void)d_ws; (void)ws_size; (void)out_size;
    const float* x1 = (const float*)d_in[0];
    const float* x2 = (const float*)d_in[1];
    float* out = (float*)d_out;

    norm_cast_kernel<<<2 * NROWS, 256, 0, stream>>>(x1, x2);
    gemm8_kernel<<<(NROWS / 256) * (NROWS / 256), 512, 0, stream>>>(out);
}